// Round 1
// baseline (471.118 us; speedup 1.0000x reference)
//
#include <hip/hip_runtime.h>

#define QMAX 127.0f

// Problem constants (fixed by setup_inputs)
#define B_  64
#define C_  1024
#define H_  28
#define W__ 28
#define HW_ 784       // 28*28
#define R_  256
#define N_TOTAL (B_*C_*HW_)      // 51,380,224
#define N4_TOTAL (N_TOTAL/4)     // 12,845,056

// ws layout (float offsets)
// [0] am_x, [1] am_w1, [2] am_w2, [3] am_mean, [4] am_h
#define MEAN_OFF 8                        // 65536 floats (B*C)
#define H_OFF    (MEAN_OFF + B_*C_)       // 16384 floats (B*R)
#define G_OFF    (H_OFF + B_*R_)          // 65536 floats (B*C)

__global__ __launch_bounds__(64) void k_init(float* ws) {
    if (threadIdx.x < 8) ws[threadIdx.x] = 0.0f;
}

// absmax over n4 float4 -> atomicMax into *out (bits of nonneg float compare as uint)
__global__ __launch_bounds__(256) void k_absmax4(const float4* __restrict__ p, int n4,
                                                 float* __restrict__ out) {
    float m = 0.0f;
    for (int i = blockIdx.x * blockDim.x + threadIdx.x; i < n4; i += gridDim.x * blockDim.x) {
        float4 v = p[i];
        m = fmaxf(m, fmaxf(fmaxf(fabsf(v.x), fabsf(v.y)), fmaxf(fabsf(v.z), fabsf(v.w))));
    }
    for (int o = 32; o > 0; o >>= 1) m = fmaxf(m, __shfl_down(m, o, 64));
    __shared__ float sm[4];
    int wid = threadIdx.x >> 6, lane = threadIdx.x & 63;
    if (lane == 0) sm[wid] = m;
    __syncthreads();
    if (threadIdx.x == 0) {
        float bm = fmaxf(fmaxf(sm[0], sm[1]), fmaxf(sm[2], sm[3]));
        atomicMax((unsigned int*)out, __float_as_uint(bm));
    }
}

// per-(b,c) mean of fake-quantized x. One wave per (b,c); 4 waves/block.
__global__ __launch_bounds__(256) void k_mean(const float* __restrict__ x,
                                              const float* __restrict__ ws,
                                              float* __restrict__ mean) {
    int wid = threadIdx.x >> 6, lane = threadIdx.x & 63;
    int bc = blockIdx.x * 4 + wid;            // grid = 16384 -> 65536 (b,c)
    float s = fmaxf(ws[0] / QMAX, 1e-8f);
    float rs = 1.0f / s;                      // reciprocal OK: mean path tolerance is huge (/784)
    const float4* p = (const float4*)(x + (size_t)bc * HW_);
    int isum = 0;
    #pragma unroll
    for (int j = 0; j < 4; j++) {
        int idx = lane + 64 * j;
        if (idx < HW_ / 4) {
            float4 v = p[idx];
            isum += (int)fminf(fmaxf(rintf(v.x * rs), -QMAX), QMAX);
            isum += (int)fminf(fmaxf(rintf(v.y * rs), -QMAX), QMAX);
            isum += (int)fminf(fmaxf(rintf(v.z * rs), -QMAX), QMAX);
            isum += (int)fminf(fmaxf(rintf(v.w * rs), -QMAX), QMAX);
        }
    }
    for (int o = 32; o > 0; o >>= 1) isum += __shfl_down(isum, o, 64);
    if (lane == 0) mean[bc] = (float)isum * s / (float)HW_;
}

// FC1: h[b][r] = relu( s2p*sw * sum_c k_a*k_w + b1[r] ).  One wave per output.
__global__ __launch_bounds__(256) void k_fc1(const float* __restrict__ ws,
                                             const float* __restrict__ W1,
                                             const float* __restrict__ b1,
                                             float* __restrict__ h) {
    int wid = threadIdx.x >> 6, lane = threadIdx.x & 63;
    int out = blockIdx.x * 4 + wid;           // grid = 4096 -> 16384 outputs
    int b = out >> 8, r = out & 255;
    float s2  = fmaxf(ws[3] / QMAX, 1e-8f);           // scale of fake_quant(mean)
    float s2p = fmaxf((QMAX * s2) / QMAX, 1e-8f);     // effective scale after 2nd fake_quant
    float sw  = fmaxf(ws[1] / QMAX, 1e-8f);
    const float* mrow = ws + MEAN_OFF + b * C_;
    const float* wrow = W1 + r * C_;
    int idot = 0;
    for (int c = lane; c < C_; c += 64) {
        int ka = (int)fminf(fmaxf(rintf(mrow[c] / s2), -QMAX), QMAX);
        int kw = (int)fminf(fmaxf(rintf(wrow[c] / sw), -QMAX), QMAX);
        idot += ka * kw;   // exact: |127*127|*1024 < 2^24
    }
    for (int o = 32; o > 0; o >>= 1) idot += __shfl_down(idot, o, 64);
    if (lane == 0) {
        float v = (float)idot * (s2p * sw) + b1[r];
        h[out] = fmaxf(v, 0.0f);
    }
}

// FC2 + hardsigmoid: gate[b][c]. One wave per output.
__global__ __launch_bounds__(256) void k_fc2(const float* __restrict__ ws,
                                             const float* __restrict__ W2,
                                             const float* __restrict__ b2,
                                             float* __restrict__ gate) {
    int wid = threadIdx.x >> 6, lane = threadIdx.x & 63;
    int out = blockIdx.x * 4 + wid;           // grid = 16384 -> 65536 outputs
    int b = out >> 10, c = out & 1023;
    float sh = fmaxf(ws[4] / QMAX, 1e-8f);
    float sw = fmaxf(ws[2] / QMAX, 1e-8f);
    const float* hrow = ws + H_OFF + b * R_;
    const float* wrow = W2 + c * R_;
    int idot = 0;
    #pragma unroll
    for (int r0 = 0; r0 < R_; r0 += 64) {
        int r = r0 + lane;
        int ka = (int)fminf(fmaxf(rintf(hrow[r] / sh), -QMAX), QMAX);
        int kw = (int)fminf(fmaxf(rintf(wrow[r] / sw), -QMAX), QMAX);
        idot += ka * kw;
    }
    for (int o = 32; o > 0; o >>= 1) idot += __shfl_down(idot, o, 64);
    if (lane == 0) {
        float t = (float)idot * (sh * sw) + b2[c];
        gate[out] = fminf(fmaxf(t / 6.0f + 0.5f, 0.0f), 1.0f);
    }
}

// out = x * gate[bc], float4 streams
__global__ __launch_bounds__(256) void k_scale(const float* __restrict__ x,
                                               const float* __restrict__ gate,
                                               float* __restrict__ out) {
    const float4* xv = (const float4*)x;
    float4* ov = (float4*)out;
    for (unsigned i = blockIdx.x * blockDim.x + threadIdx.x; i < (unsigned)N4_TOTAL;
         i += gridDim.x * blockDim.x) {
        unsigned bc = i / (HW_ / 4);          // 196 float4 per (b,c); magic-mul div
        float g = gate[bc];
        float4 v = xv[i];
        v.x *= g; v.y *= g; v.z *= g; v.w *= g;
        ov[i] = v;
    }
}

extern "C" void kernel_launch(void* const* d_in, const int* in_sizes, int n_in,
                              void* d_out, int out_size, void* d_ws, size_t ws_size,
                              hipStream_t stream) {
    const float* x  = (const float*)d_in[0];
    const float* W1 = (const float*)d_in[1];
    const float* b1 = (const float*)d_in[2];
    const float* W2 = (const float*)d_in[3];
    const float* b2 = (const float*)d_in[4];
    float* out = (float*)d_out;
    float* ws  = (float*)d_ws;

    k_init<<<1, 64, 0, stream>>>(ws);
    // absmax of x, W1, W2
    k_absmax4<<<2048, 256, 0, stream>>>((const float4*)x,  N4_TOTAL,      ws + 0);
    k_absmax4<<<64,   256, 0, stream>>>((const float4*)W1, (R_*C_)/4,     ws + 1);
    k_absmax4<<<64,   256, 0, stream>>>((const float4*)W2, (C_*R_)/4,     ws + 2);
    // quantized global avg-pool
    k_mean<<<(B_*C_)/4, 256, 0, stream>>>(x, ws, ws + MEAN_OFF);
    k_absmax4<<<32, 256, 0, stream>>>((const float4*)(ws + MEAN_OFF), (B_*C_)/4, ws + 3);
    // FC1 + relu, then absmax of h
    k_fc1<<<(B_*R_)/4, 256, 0, stream>>>(ws, W1, b1, ws + H_OFF);
    k_absmax4<<<16, 256, 0, stream>>>((const float4*)(ws + H_OFF), (B_*R_)/4, ws + 4);
    // FC2 + hardsigmoid
    k_fc2<<<(B_*C_)/4, 256, 0, stream>>>(ws, W2, b2, ws + G_OFF);
    // broadcast scale
    k_scale<<<8192, 256, 0, stream>>>(x, ws + G_OFF, out);
}

// Round 3
// 431.092 us; speedup vs baseline: 1.0928x; 1.0928x over previous
//
#include <hip/hip_runtime.h>

#define QMAX 127.0f
#define B_   64
#define C_   1024
#define HW_  784
#define R_   256
#define NROW 65536                 // B*C
#define N4_TOTAL 12845056          // B*C*HW/4
#define ROW4 196                   // HW/4

typedef float fx4 __attribute__((ext_vector_type(4)));   // native vec: nontemporal-store OK

// ws float offsets
#define PX_OFF   0                 // 1024 per-block partial max |x|
#define PW1_OFF  1024              // 1024 partial max |W1|
#define PW2_OFF  2048              // 1024 partial max |W2|
#define PM_OFF   3072              // 1024 partial max |mean|
#define PH_OFF   4096              // 1024 partial max h
#define MEAN_OFF 8192              // 65536 floats
#define H_OFF    (MEAN_OFF + NROW)       // 16384 floats
#define GATE_OFF (H_OFF + B_*R_)         // 65536 floats

__device__ __forceinline__ float block_max(float v, volatile float* sm) {
    #pragma unroll
    for (int o = 32; o > 0; o >>= 1) v = fmaxf(v, __shfl_xor(v, o, 64));
    int lane = threadIdx.x & 63, wid = threadIdx.x >> 6;
    if (lane == 0) sm[wid] = v;
    __syncthreads();
    float r = fmaxf(fmaxf(sm[0], sm[1]), fmaxf(sm[2], sm[3]));
    __syncthreads();               // safe for helper reuse
    return r;
}

__device__ __forceinline__ float amax4(float4 v) {
    return fmaxf(fmaxf(fabsf(v.x), fabsf(v.y)), fmaxf(fabsf(v.z), fabsf(v.w)));
}

__device__ __forceinline__ int q1(float v, float rs) {
    return (int)fminf(fmaxf(rintf(v * rs), -QMAX), QMAX);
}

__device__ __forceinline__ int q4sum(float4 v, float rs) {
    return q1(v.x, rs) + q1(v.y, rs) + q1(v.z, rs) + q1(v.w, rs);
}

// ---- kA: absmax of x, W1, W2 -> per-block partials. grid 1024x256 ----
__global__ __launch_bounds__(256) void kA(const float4* __restrict__ x,
                                          const float4* __restrict__ w1,
                                          const float4* __restrict__ w2,
                                          float* __restrict__ ws) {
    __shared__ float sm[4];
    int tid = blockIdx.x * 256 + threadIdx.x;          // 262144 threads
    float mx = 0.0f;
    #pragma unroll 7                                   // 49 = 7*7 exact iterations
    for (int j = 0; j < 49; j++) mx = fmaxf(mx, amax4(x[tid + j * 262144]));
    float m1 = (tid < 65536) ? amax4(w1[tid]) : 0.0f;  // W1: 65536 float4
    float m2 = (tid < 65536) ? amax4(w2[tid]) : 0.0f;
    float bx  = block_max(mx, sm);
    float b1m = block_max(m1, sm);
    float b2m = block_max(m2, sm);
    if (threadIdx.x == 0) {
        ws[PX_OFF  + blockIdx.x] = bx;
        ws[PW1_OFF + blockIdx.x] = b1m;
        ws[PW2_OFF + blockIdx.x] = b2m;
    }
}

// ---- kB: quantized per-(b,c) mean + |mean| partials. grid 2048x256, 8 rows/wave ----
__global__ __launch_bounds__(256) void kB(const float* __restrict__ x,
                                          float* __restrict__ ws) {
    __shared__ float sm[4];
    int t = threadIdx.x;
    const float* px = ws + PX_OFF;
    float v = fmaxf(fmaxf(px[t], px[t + 256]), fmaxf(px[t + 512], px[t + 768]));
    float gmax = block_max(v, sm);
    float s  = fmaxf(gmax / QMAX, 1e-8f);
    float rs = 1.0f / s;
    int wid = t >> 6, lane = t & 63;
    int gw = blockIdx.x * 4 + wid;                     // 8192 waves
    float wmax = 0.0f;
    #pragma unroll
    for (int k = 0; k < 8; k++) {
        int bc = gw * 8 + k;
        const float4* p = (const float4*)(x + (size_t)bc * HW_);
        int isum = 0;
        #pragma unroll
        for (int j = 0; j < 3; j++) isum += q4sum(p[lane + 64 * j], rs);
        if (lane < 4) isum += q4sum(p[192 + lane], rs);
        #pragma unroll
        for (int o = 32; o > 0; o >>= 1) isum += __shfl_xor(isum, o, 64);
        float m = (float)isum * s / 784.0f;
        if (lane == 0) ws[MEAN_OFF + bc] = m;
        wmax = fmaxf(wmax, fabsf(m));
    }
    float bm = block_max(wmax, sm);
    if (t == 0) ws[PM_OFF + blockIdx.x] = bm;
}

// ---- kC: FC1 + relu + h partials. grid 1024x256, 4 outputs/wave ----
__global__ __launch_bounds__(256) void kC(const float* __restrict__ W1,
                                          const float* __restrict__ b1,
                                          float* __restrict__ ws) {
    __shared__ float sm[4];
    int t = threadIdx.x;
    const float* pm = ws + PM_OFF;
    const float* pw = ws + PW1_OFF;
    float vm = fmaxf(fmaxf(pm[t], pm[t + 256]), fmaxf(pm[t + 512], pm[t + 768]));
    float vw = fmaxf(fmaxf(pw[t], pw[t + 256]), fmaxf(pw[t + 512], pw[t + 768]));
    float mmax = block_max(vm, sm);
    float wmx  = block_max(vw, sm);
    float s2  = fmaxf(mmax / QMAX, 1e-8f);
    float s2q = fmaxf((QMAX * s2) / QMAX, 1e-8f);       // effective scale after 2nd fake_quant
    float sw  = fmaxf(wmx / QMAX, 1e-8f);
    float rs2 = 1.0f / s2, rsw = 1.0f / sw;
    int wid = t >> 6, lane = t & 63;
    int gw = blockIdx.x * 4 + wid;                      // 4096 waves
    float hmax = 0.0f;
    #pragma unroll
    for (int k = 0; k < 4; k++) {
        int out = gw * 4 + k;                           // 16384 outputs
        int b = out >> 8, r = out & 255;
        const float4* mrow = (const float4*)(ws + MEAN_OFF + b * C_);
        const float4* wrow = (const float4*)(W1 + r * C_);
        int idot = 0;
        #pragma unroll
        for (int j = 0; j < 4; j++) {
            float4 mv = mrow[lane + 64 * j];
            float4 wv = wrow[lane + 64 * j];
            idot += q1(mv.x, rs2) * q1(wv.x, rsw) + q1(mv.y, rs2) * q1(wv.y, rsw)
                  + q1(mv.z, rs2) * q1(wv.z, rsw) + q1(mv.w, rs2) * q1(wv.w, rsw);
        }
        #pragma unroll
        for (int o = 32; o > 0; o >>= 1) idot += __shfl_xor(idot, o, 64);
        float hv = fmaxf((float)idot * (s2q * sw) + b1[r], 0.0f);
        if (lane == 0) ws[H_OFF + out] = hv;
        hmax = fmaxf(hmax, hv);
    }
    float bh = block_max(hmax, sm);
    if (t == 0) ws[PH_OFF + blockIdx.x] = bh;
}

// ---- kD: FC2 + hardsigmoid -> gate. grid 1024x256, 16 outputs/wave ----
__global__ __launch_bounds__(256) void kD(const float* __restrict__ W2,
                                          const float* __restrict__ b2,
                                          float* __restrict__ ws) {
    __shared__ float sm[4];
    int t = threadIdx.x;
    const float* ph = ws + PH_OFF;
    const float* pw = ws + PW2_OFF;
    float vh = fmaxf(fmaxf(ph[t], ph[t + 256]), fmaxf(ph[t + 512], ph[t + 768]));
    float vw = fmaxf(fmaxf(pw[t], pw[t + 256]), fmaxf(pw[t + 512], pw[t + 768]));
    float hmx = block_max(vh, sm);
    float wmx = block_max(vw, sm);
    float sh = fmaxf(hmx / QMAX, 1e-8f);                // h is raw (single fake_quant)
    float sw = fmaxf(wmx / QMAX, 1e-8f);
    float rsh = 1.0f / sh, rsw = 1.0f / sw;
    int wid = t >> 6, lane = t & 63;
    int gw = blockIdx.x * 4 + wid;                      // 4096 waves
    #pragma unroll
    for (int k = 0; k < 16; k++) {
        int out = gw * 16 + k;                          // 65536 outputs
        int b = out >> 10, c = out & 1023;
        const float4* hrow = (const float4*)(ws + H_OFF + b * R_);
        const float4* wrow = (const float4*)(W2 + c * R_);
        float4 hv = hrow[lane];                         // 64 float4 = full 256 row
        float4 wv = wrow[lane];
        int idot = q1(hv.x, rsh) * q1(wv.x, rsw) + q1(hv.y, rsh) * q1(wv.y, rsw)
                 + q1(hv.z, rsh) * q1(wv.z, rsw) + q1(hv.w, rsh) * q1(wv.w, rsw);
        #pragma unroll
        for (int o = 32; o > 0; o >>= 1) idot += __shfl_xor(idot, o, 64);
        if (lane == 0) {
            float tv = (float)idot * (sh * sw) + b2[c];
            ws[GATE_OFF + out] = fminf(fmaxf(tv / 6.0f + 0.5f, 0.0f), 1.0f);
        }
    }
}

// ---- kE: out = x * gate, row-structured, nontemporal stores. grid 2048x256, 8 rows/wave ----
__global__ __launch_bounds__(256) void kE(const float* __restrict__ x,
                                          const float* __restrict__ ws,
                                          float* __restrict__ out) {
    int t = threadIdx.x;
    int wid = t >> 6, lane = t & 63;
    int gw = blockIdx.x * 4 + wid;                      // 8192 waves
    #pragma unroll
    for (int k = 0; k < 8; k++) {
        int bc = gw * 8 + k;
        float g = ws[GATE_OFF + bc];
        const fx4* p = (const fx4*)(x + (size_t)bc * HW_);
        fx4* o = (fx4*)(out + (size_t)bc * HW_);
        #pragma unroll
        for (int j = 0; j < 3; j++) {
            fx4 v = p[lane + 64 * j];
            v *= g;
            __builtin_nontemporal_store(v, &o[lane + 64 * j]);
        }
        if (lane < 4) {
            fx4 v = p[192 + lane];
            v *= g;
            __builtin_nontemporal_store(v, &o[192 + lane]);
        }
    }
}

extern "C" void kernel_launch(void* const* d_in, const int* in_sizes, int n_in,
                              void* d_out, int out_size, void* d_ws, size_t ws_size,
                              hipStream_t stream) {
    const float* x  = (const float*)d_in[0];
    const float* W1 = (const float*)d_in[1];
    const float* b1 = (const float*)d_in[2];
    const float* W2 = (const float*)d_in[3];
    const float* b2 = (const float*)d_in[4];
    float* out = (float*)d_out;
    float* ws  = (float*)d_ws;

    kA<<<1024, 256, 0, stream>>>((const float4*)x, (const float4*)W1, (const float4*)W2, ws);
    kB<<<2048, 256, 0, stream>>>(x, ws);
    kC<<<1024, 256, 0, stream>>>(W1, b1, ws);
    kD<<<1024, 256, 0, stream>>>(W2, b2, ws);
    kE<<<2048, 256, 0, stream>>>(x, ws, out);
}